// Round 2
// baseline (338.520 us; speedup 1.0000x reference)
//
#include <hip/hip_runtime.h>
#include <hip/hip_bf16.h>

typedef __bf16 bf16x8 __attribute__((ext_vector_type(8)));
typedef __bf16 bf16x4 __attribute__((ext_vector_type(4)));
typedef float  f32x4  __attribute__((ext_vector_type(4)));

#define GLOBAL_AS __attribute__((address_space(1)))
#define LDS_AS    __attribute__((address_space(3)))

__device__ __forceinline__ void glds16(const void* g, void* l) {
  __builtin_amdgcn_global_load_lds((const GLOBAL_AS void*)g, (LDS_AS void*)l, 16, 0, 0);
}

// ---------------- f32 -> bf16 convert ----------------
__global__ __launch_bounds__(256) void cvt_kernel(const float* __restrict__ src,
                                                  __bf16* __restrict__ dst, int n4) {
  int i = blockIdx.x * 256 + threadIdx.x;
  if (i < n4) {
    float4 f = ((const float4*)src)[i];
    bf16x4 o;
    o[0] = (__bf16)f.x; o[1] = (__bf16)f.y; o[2] = (__bf16)f.z; o[3] = (__bf16)f.w;
    ((bf16x4*)dst)[i] = o;
  }
}

// ---------------- RoPE cos/sin table: [l][j] l<2048, j<32 ----------------
__global__ __launch_bounds__(256) void rope_tab_kernel(float2* __restrict__ tab) {
  int i = blockIdx.x * 256 + threadIdx.x;   // 0..65535
  int l = i >> 5, j = i & 31;
  float inv = 1.0f / powf(10000.0f, (float)j * (1.0f / 32.0f));
  float ang = (float)l * inv;
  tab[i] = make_float2(cosf(ang), sinf(ang));
}

// ---------------- GEMM C = A * B^T (+bias), A[M,K] bf16, B[N,K] bf16 ----------------
// 128x128 tile, BK=32, 4 waves (2x2), 16x16x32 bf16 MFMA.
// EPI 0: scatter->q/k/v (bf16); EPI 1: d_out (f32).
template <int EPI>
__global__ __launch_bounds__(256) void gemm_bt(
    const __bf16* __restrict__ A, const __bf16* __restrict__ Bm, int K,
    const float* __restrict__ bias,
    __bf16* __restrict__ qo, __bf16* __restrict__ ko, __bf16* __restrict__ vo,
    float* __restrict__ out) {
  __shared__ __bf16 As[128 * 32];
  __shared__ __bf16 Bs[128 * 32];
  const int t = threadIdx.x;
  const int bn = blockIdx.x, bm = blockIdx.y;
  const int lane = t & 63, w = t >> 6;
  const int wr = w >> 1, wc = w & 1;
  const int lr = lane & 15, lg = lane >> 4;
  const size_t rowA0 = (size_t)bm * 128, rowB0 = (size_t)bn * 128;

  f32x4 acc[4][4] = {};

  for (int k0 = 0; k0 < K; k0 += 32) {
    __syncthreads();
#pragma unroll
    for (int i = 0; i < 2; ++i) {
      int c = t + i * 256;
      int rr = c >> 2, c8 = (c & 3) * 8;
      glds16(A + (rowA0 + rr) * K + k0 + c8, As + c * 8);
      glds16(Bm + (rowB0 + rr) * K + k0 + c8, Bs + c * 8);
    }
    __syncthreads();
    bf16x8 af[4], bfr[4];
#pragma unroll
    for (int i = 0; i < 4; ++i) {
      af[i]  = *(const bf16x8*)&As[(wr * 64 + i * 16 + lr) * 32 + lg * 8];
      bfr[i] = *(const bf16x8*)&Bs[(wc * 64 + i * 16 + lr) * 32 + lg * 8];
    }
#pragma unroll
    for (int mi = 0; mi < 4; ++mi)
#pragma unroll
      for (int ni = 0; ni < 4; ++ni)
        acc[mi][ni] = __builtin_amdgcn_mfma_f32_16x16x32_bf16(af[mi], bfr[ni], acc[mi][ni], 0, 0, 0);
  }

  // epilogue: C/D layout col=lane&15, row=(lane>>4)*4+reg (m89-verified)
#pragma unroll
  for (int mi = 0; mi < 4; ++mi) {
    int m0 = bm * 128 + wr * 64 + mi * 16 + lg * 4;
#pragma unroll
    for (int ni = 0; ni < 4; ++ni) {
      int n = bn * 128 + wc * 64 + ni * 16 + lr;
      float bb = bias[n];
      if constexpr (EPI == 0) {
        int sect = n >> 10, h = (n >> 6) & 15, d = n & 63;
        __bf16* dst = (sect == 0) ? qo : ((sect == 1) ? ko : vo);
#pragma unroll
        for (int r = 0; r < 4; ++r) {
          int m = m0 + r;
          int bb_ = m >> 11, l = m & 2047;
          float val = acc[mi][ni][r] + bb;
          dst[(((size_t)(bb_ * 16 + h)) * 2048 + l) * 64 + d] = (__bf16)val;
        }
      } else {
#pragma unroll
        for (int r = 0; r < 4; ++r) {
          int m = m0 + r;
          out[(size_t)m * 1024 + n] = acc[mi][ni][r] + bb;
        }
      }
    }
  }
}

// ---------------- RMSNorm + RoPE, in-place on q and k ([b][h][l][64] bf16) ----------------
__global__ __launch_bounds__(256) void norm_rope_kernel(
    __bf16* __restrict__ qb, __bf16* __restrict__ kb,
    const float* __restrict__ qg, const float* __restrict__ kg,
    const float2* __restrict__ tab) {
  const int lane = threadIdx.x & 63;
  const int w0 = (blockIdx.x * 256 + threadIdx.x) >> 6;
  const int nw = gridDim.x * 4;
  for (int rid = w0; rid < 131072; rid += nw) {
    const int tsel = rid >> 16;      // 0: q, 1: k
    const int r = rid & 65535;
    __bf16* buf = tsel ? kb : qb;
    const float* g = tsel ? kg : qg;
    const int l = r & 2047;
    const size_t base = (size_t)r * 64;
    float v = (float)buf[base + lane];
    float ss = v * v;
    ss += __shfl_xor(ss, 1);  ss += __shfl_xor(ss, 2);  ss += __shfl_xor(ss, 4);
    ss += __shfl_xor(ss, 8);  ss += __shfl_xor(ss, 16); ss += __shfl_xor(ss, 32);
    float tnorm = v * rsqrtf(ss * (1.0f / 64.0f) + 1e-6f) * g[lane];
    float2 cs = tab[l * 32 + (lane & 31)];
    float partner = __shfl_xor(tnorm, 32);
    float o = (lane < 32) ? (tnorm * cs.x - partner * cs.y)
                          : (tnorm * cs.x + partner * cs.y);
    buf[base + lane] = (__bf16)o;
  }
}

// ---------------- flash attention, block-causal by 128-token frames ----------------
// grid (16 fq, 32 bh); 256 thr = 4 waves x 32 q-rows. LDS XOR-swizzled.
__global__ __launch_bounds__(256) void attn_kernel(
    const __bf16* __restrict__ qb, const __bf16* __restrict__ kb,
    const __bf16* __restrict__ vb, __bf16* __restrict__ ob) {
  __shared__ char smem[81920];
  char* Qs = smem;            // [128][64] bf16, swz: byte ^= (row&7)<<4
  char* Ks = smem + 16384;    // same
  char* Vt = smem + 32768;    // [64][128] bf16 (V^T), swz: byte ^= (row&15)<<4
  char* Ps = smem + 49152;    // [128][128] bf16, swz: byte ^= (row&15)<<4

  const int fq = blockIdx.x;
  const int bh = blockIdx.y;
  const int t = threadIdx.x;
  const int lane = t & 63;
  const int w = t >> 6;
  const int lr = lane & 15, lg = lane >> 4;
  const size_t hoff = (size_t)bh * (2048 * 64);

  // stage Q
#pragma unroll
  for (int i = 0; i < 4; ++i) {
    int c = t + i * 256;
    int row = c >> 3, s8 = c & 7;
    bf16x8 val = *(const bf16x8*)(qb + hoff + (size_t)(fq * 128 + row) * 64 + s8 * 8);
    *(bf16x8*)(Qs + row * 128 + ((s8 * 16) ^ ((row & 7) << 4))) = val;
  }

  f32x4 acc[2][4] = {};
  float m_run[2][4], l_run[2][4];
#pragma unroll
  for (int a = 0; a < 2; ++a)
#pragma unroll
    for (int r = 0; r < 4; ++r) { m_run[a][r] = -INFINITY; l_run[a][r] = 0.0f; }

  const int fk0 = (fq == 15) ? 1 : 0;
  for (int fk = fk0; fk <= fq; ++fk) {
    __syncthreads();
#pragma unroll
    for (int i = 0; i < 4; ++i) {   // stage K
      int c = t + i * 256;
      int row = c >> 3, s8 = c & 7;
      bf16x8 val = *(const bf16x8*)(kb + hoff + (size_t)(fk * 128 + row) * 64 + s8 * 8);
      *(bf16x8*)(Ks + row * 128 + ((s8 * 16) ^ ((row & 7) << 4))) = val;
    }
#pragma unroll
    for (int i = 0; i < 4; ++i) {   // stage V transposed
      int c = t + i * 256;
      int row = c >> 3, s8 = c & 7;
      bf16x8 val = *(const bf16x8*)(vb + hoff + (size_t)(fk * 128 + row) * 64 + s8 * 8);
#pragma unroll
      for (int j = 0; j < 8; ++j) {
        int d = s8 * 8 + j;
        *(__bf16*)(Vt + d * 256 + ((row * 2) ^ ((d & 15) << 4))) = val[j];
      }
    }
    __syncthreads();

    // S = Q K^T
    f32x4 s[2][8] = {};
#pragma unroll
    for (int kk = 0; kk < 2; ++kk) {
      bf16x8 aq[2];
#pragma unroll
      for (int mf = 0; mf < 2; ++mf) {
        int row = w * 32 + mf * 16 + lr;
        aq[mf] = *(const bf16x8*)(Qs + row * 128 + ((kk * 64 + lg * 16) ^ ((row & 7) << 4)));
      }
#pragma unroll
      for (int nf = 0; nf < 8; ++nf) {
        int rowk = nf * 16 + lr;
        bf16x8 bk = *(const bf16x8*)(Ks + rowk * 128 + ((kk * 64 + lg * 16) ^ ((rowk & 7) << 4)));
#pragma unroll
        for (int mf = 0; mf < 2; ++mf)
          s[mf][nf] = __builtin_amdgcn_mfma_f32_16x16x32_bf16(aq[mf], bk, s[mf][nf], 0, 0, 0);
      }
    }

    // online softmax (rows: w*32 + mf*16 + lg*4 + r; 16 lanes lr share a row)
#pragma unroll
    for (int mf = 0; mf < 2; ++mf) {
#pragma unroll
      for (int r = 0; r < 4; ++r) {
        float mx = s[mf][0][r];
#pragma unroll
        for (int nf = 1; nf < 8; ++nf) mx = fmaxf(mx, s[mf][nf][r]);
        mx *= 0.125f;
        mx = fmaxf(mx, __shfl_xor(mx, 1));
        mx = fmaxf(mx, __shfl_xor(mx, 2));
        mx = fmaxf(mx, __shfl_xor(mx, 4));
        mx = fmaxf(mx, __shfl_xor(mx, 8));
        float mnew = fmaxf(m_run[mf][r], mx);
        float cr = __expf(m_run[mf][r] - mnew);
        float lsum = 0.0f;
#pragma unroll
        for (int nf = 0; nf < 8; ++nf) {
          float p = __expf(s[mf][nf][r] * 0.125f - mnew);
          s[mf][nf][r] = p;
          lsum += p;
        }
        lsum += __shfl_xor(lsum, 1);
        lsum += __shfl_xor(lsum, 2);
        lsum += __shfl_xor(lsum, 4);
        lsum += __shfl_xor(lsum, 8);
        l_run[mf][r] = l_run[mf][r] * cr + lsum;
        m_run[mf][r] = mnew;
#pragma unroll
        for (int df = 0; df < 4; ++df) acc[mf][df][r] *= cr;
      }
#pragma unroll
      for (int nf = 0; nf < 8; ++nf) {
#pragma unroll
        for (int r = 0; r < 4; ++r) {
          int row = w * 32 + mf * 16 + lg * 4 + r;
          int colb = (nf * 16 + lr) * 2;
          *(__bf16*)(Ps + row * 256 + (colb ^ ((row & 15) << 4))) = (__bf16)s[mf][nf][r];
        }
      }
    }

    // O += P V  (A-frags from Ps, B-frags from Vt; wave reads only its own P rows)
#pragma unroll
    for (int ks = 0; ks < 4; ++ks) {
      bf16x8 ap[2];
#pragma unroll
      for (int mf = 0; mf < 2; ++mf) {
        int row = w * 32 + mf * 16 + lr;
        ap[mf] = *(const bf16x8*)(Ps + row * 256 + ((ks * 64 + lg * 16) ^ ((row & 15) << 4)));
      }
#pragma unroll
      for (int df = 0; df < 4; ++df) {
        int rv = df * 16 + lr;
        bf16x8 bv = *(const bf16x8*)(Vt + rv * 256 + ((ks * 64 + lg * 16) ^ ((rv & 15) << 4)));
#pragma unroll
        for (int mf = 0; mf < 2; ++mf)
          acc[mf][df] = __builtin_amdgcn_mfma_f32_16x16x32_bf16(ap[mf], bv, acc[mf][df], 0, 0, 0);
      }
    }
  }

  const int b = bh >> 4, h = bh & 15;
#pragma unroll
  for (int mf = 0; mf < 2; ++mf) {
#pragma unroll
    for (int df = 0; df < 4; ++df) {
#pragma unroll
      for (int r = 0; r < 4; ++r) {
        int l = fq * 128 + w * 32 + mf * 16 + lg * 4 + r;
        int d = df * 16 + lr;
        float o = acc[mf][df][r] / l_run[mf][r];
        ob[((size_t)(b * 2048 + l)) * 1024 + h * 64 + d] = (__bf16)o;
      }
    }
  }
}

// ---------------- launch ----------------
extern "C" void kernel_launch(void* const* d_in, const int* in_sizes, int n_in,
                              void* d_out, int out_size, void* d_ws, size_t ws_size,
                              hipStream_t stream) {
  (void)in_sizes; (void)n_in; (void)out_size; (void)ws_size;
  const float* x    = (const float*)d_in[0];
  const float* Wqkv = (const float*)d_in[1];
  const float* bqkv = (const float*)d_in[2];
  const float* Wout = (const float*)d_in[3];
  const float* bout = (const float*)d_in[4];
  const float* qg   = (const float*)d_in[5];
  const float* kg   = (const float*)d_in[6];

  char* ws = (char*)d_ws;
  __bf16* xb   = (__bf16*)(ws);                 // 4096x1024       (8 MB)
  __bf16* wqb  = (__bf16*)(ws + 8388608);       // 3072x1024       (6 MB)
  __bf16* wob  = (__bf16*)(ws + 14680064);      // 1024x1024       (2 MB)
  __bf16* qbuf = (__bf16*)(ws + 16777216);      // [2][16][2048][64]
  __bf16* kbuf = (__bf16*)(ws + 25165824);
  __bf16* vbuf = (__bf16*)(ws + 33554432);
  __bf16* aob  = (__bf16*)(ws + 41943040);      // [2][2048][1024]
  float2* rtab = (float2*)(ws + 50331648);      // [2048][32] cos/sin

  cvt_kernel<<<4096, 256, 0, stream>>>(x, xb, 1048576);
  cvt_kernel<<<3072, 256, 0, stream>>>(Wqkv, wqb, 786432);
  cvt_kernel<<<1024, 256, 0, stream>>>(Wout, wob, 262144);
  rope_tab_kernel<<<256, 256, 0, stream>>>(rtab);
  gemm_bt<0><<<dim3(24, 32), 256, 0, stream>>>(xb, wqb, 1024, bqkv, qbuf, kbuf, vbuf, nullptr);
  norm_rope_kernel<<<512, 256, 0, stream>>>(qbuf, kbuf, qg, kg, rtab);
  attn_kernel<<<dim3(16, 32), 256, 0, stream>>>(qbuf, kbuf, vbuf, aob);
  gemm_bt<1><<<dim3(8, 32), 256, 0, stream>>>(aob, wob, 1024, bout, nullptr, nullptr, nullptr, (float*)d_out);
}

// Round 3
// 282.066 us; speedup vs baseline: 1.2001x; 1.2001x over previous
//
#include <hip/hip_runtime.h>
#include <hip/hip_bf16.h>

typedef __bf16 bf16x8 __attribute__((ext_vector_type(8)));
typedef __bf16 bf16x4 __attribute__((ext_vector_type(4)));
typedef float  f32x4  __attribute__((ext_vector_type(4)));

#define GLOBAL_AS __attribute__((address_space(1)))
#define LDS_AS    __attribute__((address_space(3)))

__device__ __forceinline__ void glds16(const void* g, void* l) {
  __builtin_amdgcn_global_load_lds((const GLOBAL_AS void*)g, (LDS_AS void*)l, 16, 0, 0);
}

// ---------------- f32 -> bf16 convert ----------------
__global__ __launch_bounds__(256) void cvt_kernel(const float* __restrict__ src,
                                                  __bf16* __restrict__ dst, int n4) {
  int i = blockIdx.x * 256 + threadIdx.x;
  if (i < n4) {
    float4 f = ((const float4*)src)[i];
    bf16x4 o;
    o[0] = (__bf16)f.x; o[1] = (__bf16)f.y; o[2] = (__bf16)f.z; o[3] = (__bf16)f.w;
    ((bf16x4*)dst)[i] = o;
  }
}

// ---------------- RoPE cos/sin table: [l][j] l<2048, j<32 ----------------
__global__ __launch_bounds__(256) void rope_tab_kernel(float2* __restrict__ tab) {
  int i = blockIdx.x * 256 + threadIdx.x;   // 0..65535
  int l = i >> 5, j = i & 31;
  float inv = 1.0f / powf(10000.0f, (float)j * (1.0f / 32.0f));
  float ang = (float)l * inv;
  tab[i] = make_float2(cosf(ang), sinf(ang));
}

// ---------------- GEMM C = A * B^T (+bias), A[M,K] bf16, B[N,K] bf16 ----------------
// 128x128 tile, BK=32, 4 waves (2x2), 16x16x32 bf16 MFMA. 1-D grid + XCD swizzle.
// EPI 0: scatter-> q/k [b,h,l,d] bf16, v TRANSPOSED [b,h,d,l] bf16; EPI 1: d_out f32.
template <int EPI>
__global__ __launch_bounds__(256) void gemm_bt(
    const __bf16* __restrict__ A, const __bf16* __restrict__ Bm, int K, int nbn,
    const float* __restrict__ bias,
    __bf16* __restrict__ qo, __bf16* __restrict__ ko, __bf16* __restrict__ vo,
    float* __restrict__ out) {
  __shared__ __bf16 As[128 * 32];
  __shared__ __bf16 Bs[128 * 32];
  const int t = threadIdx.x;
  // bijective XCD swizzle (grid multiple of 8)
  const int nwg = gridDim.x;
  const int id = blockIdx.x;
  const int swz = (id & 7) * (nwg >> 3) + (id >> 3);
  const int bn = swz % nbn, bm = swz / nbn;
  const int lane = t & 63, w = t >> 6;
  const int wr = w >> 1, wc = w & 1;
  const int lr = lane & 15, lg = lane >> 4;
  const size_t rowA0 = (size_t)bm * 128, rowB0 = (size_t)bn * 128;

  f32x4 acc[4][4] = {};

  for (int k0 = 0; k0 < K; k0 += 32) {
    __syncthreads();
#pragma unroll
    for (int i = 0; i < 2; ++i) {
      int c = t + i * 256;
      int rr = c >> 2, c8 = (c & 3) * 8;
      glds16(A + (rowA0 + rr) * K + k0 + c8, As + c * 8);
      glds16(Bm + (rowB0 + rr) * K + k0 + c8, Bs + c * 8);
    }
    __syncthreads();
    bf16x8 af[4], bfr[4];
#pragma unroll
    for (int i = 0; i < 4; ++i) {
      af[i]  = *(const bf16x8*)&As[(wr * 64 + i * 16 + lr) * 32 + lg * 8];
      bfr[i] = *(const bf16x8*)&Bs[(wc * 64 + i * 16 + lr) * 32 + lg * 8];
    }
#pragma unroll
    for (int mi = 0; mi < 4; ++mi)
#pragma unroll
      for (int ni = 0; ni < 4; ++ni)
        acc[mi][ni] = __builtin_amdgcn_mfma_f32_16x16x32_bf16(af[mi], bfr[ni], acc[mi][ni], 0, 0, 0);
  }

  // epilogue: C/D layout col=lane&15, row=(lane>>4)*4+reg (m89-verified)
#pragma unroll
  for (int mi = 0; mi < 4; ++mi) {
    int m0 = bm * 128 + wr * 64 + mi * 16 + lg * 4;
#pragma unroll
    for (int ni = 0; ni < 4; ++ni) {
      int n = bn * 128 + wc * 64 + ni * 16 + lr;
      float bb = bias[n];
      if constexpr (EPI == 0) {
        int sect = n >> 10, h = (n >> 6) & 15, d = n & 63;
#pragma unroll
        for (int r = 0; r < 4; ++r) {
          int m = m0 + r;
          int b_ = m >> 11, l = m & 2047;
          float val = acc[mi][ni][r] + bb;
          if (sect == 2)
            vo[((size_t)((b_ * 16 + h) * 64 + d)) * 2048 + l] = (__bf16)val;   // V^T [b,h,d,l]
          else {
            __bf16* dst = sect ? ko : qo;
            dst[(((size_t)(b_ * 16 + h)) * 2048 + l) * 64 + d] = (__bf16)val;
          }
        }
      } else {
#pragma unroll
        for (int r = 0; r < 4; ++r) {
          int m = m0 + r;
          out[(size_t)m * 1024 + n] = acc[mi][ni][r] + bb;
        }
      }
    }
  }
}

// ---------------- RMSNorm + RoPE, in-place on q and k ([b][h][l][64] bf16) ----------------
__global__ __launch_bounds__(256) void norm_rope_kernel(
    __bf16* __restrict__ qb, __bf16* __restrict__ kb,
    const float* __restrict__ qg, const float* __restrict__ kg,
    const float2* __restrict__ tab) {
  const int lane = threadIdx.x & 63;
  const int w0 = (blockIdx.x * 256 + threadIdx.x) >> 6;
  const int nw = gridDim.x * 4;
  for (int rid = w0; rid < 131072; rid += nw) {
    const int tsel = rid >> 16;      // 0: q, 1: k
    const int r = rid & 65535;
    __bf16* buf = tsel ? kb : qb;
    const float* g = tsel ? kg : qg;
    const int l = r & 2047;
    const size_t base = (size_t)r * 64;
    float v = (float)buf[base + lane];
    float ss = v * v;
    ss += __shfl_xor(ss, 1);  ss += __shfl_xor(ss, 2);  ss += __shfl_xor(ss, 4);
    ss += __shfl_xor(ss, 8);  ss += __shfl_xor(ss, 16); ss += __shfl_xor(ss, 32);
    float tnorm = v * rsqrtf(ss * (1.0f / 64.0f) + 1e-6f) * g[lane];
    float2 cs = tab[l * 32 + (lane & 31)];
    float partner = __shfl_xor(tnorm, 32);
    float o = (lane < 32) ? (tnorm * cs.x - partner * cs.y)
                          : (tnorm * cs.x + partner * cs.y);
    buf[base + lane] = (__bf16)o;
  }
}

// ---------------- flash attention, block-causal by 128-token frames ----------------
// 1-D grid 512 blocks, load-balanced (fq,bh) pairing. 4 waves x 32 q-rows.
// KVBLK=64, K/V^T double-buffered via glds16 with pre-swizzled source (involution s^=(row&7)).
// LDS: Qs 16K | K dbuf 2x8K | Vt dbuf 2x8K | Ps 16K = 64 KB -> 2 blocks/CU.
__global__ __launch_bounds__(256) void attn_kernel(
    const __bf16* __restrict__ qb, const __bf16* __restrict__ kb,
    const __bf16* __restrict__ vT, __bf16* __restrict__ ob) {
  __shared__ char smem[65536];
  char* Qs = smem;                       // [128][64] bf16
  char* Ps = smem + 49152;               // [128][64] bf16

  const int id = blockIdx.x;             // 0..511
  const int rank = (id < 256) ? id : 767 - id;   // pairs complementary costs on a CU
  const int fq = rank >> 5;
  const int bh = rank & 31;
  const int t = threadIdx.x;
  const int lane = t & 63;
  const int w = t >> 6;
  const int lr = lane & 15, lg = lane >> 4;
  const size_t hoff = (size_t)bh * (2048 * 64);

  // stage Q (pre-swizzled source, linear LDS)
#pragma unroll
  for (int i = 0; i < 4; ++i) {
    int c = t + i * 256;
    int row = c >> 3, sl = c & 7;
    int sp = sl ^ (row & 7);
    glds16(qb + hoff + (size_t)(fq * 128 + row) * 64 + sp * 8, Qs + c * 16);
  }

  auto stageKV = [&](int bufsel, int fk) {
    char* Kd = smem + 16384 + bufsel * 8192;
    char* Vd = smem + 32768 + bufsel * 8192;
#pragma unroll
    for (int i = 0; i < 2; ++i) {
      int c = t + i * 256;
      int row = c >> 3, sl = c & 7;
      int sp = sl ^ (row & 7);
      glds16(kb + hoff + (size_t)(fk * 64 + row) * 64 + sp * 8, Kd + c * 16);
      glds16(vT + hoff + (size_t)row * 2048 + fk * 64 + sp * 8, Vd + c * 16);
    }
  };

  const int fkStart = (fq == 15) ? 2 : 0;          // frame 0 excluded for last frame
  const int fkEnd = (fq + 1) * 2;                  // exclusive, 64-row k-tiles
  stageKV(0, fkStart);
  __syncthreads();                                 // drains vmcnt(0)

  // hoist Q fragments (reused every k-tile)
  bf16x8 aq[2][2];
#pragma unroll
  for (int kk = 0; kk < 2; ++kk)
#pragma unroll
    for (int mf = 0; mf < 2; ++mf) {
      int row = w * 32 + mf * 16 + lr;
      aq[kk][mf] = *(const bf16x8*)(Qs + row * 128 + (((kk * 4 + lg) ^ (row & 7)) << 4));
    }

  f32x4 acc[2][4] = {};
  float m_run[2][4], l_run[2][4];
#pragma unroll
  for (int a = 0; a < 2; ++a)
#pragma unroll
    for (int r = 0; r < 4; ++r) { m_run[a][r] = -INFINITY; l_run[a][r] = 0.0f; }

  int cur = 0;
  for (int fk = fkStart; fk < fkEnd; ++fk) {
    if (fk + 1 < fkEnd) stageKV(cur ^ 1, fk + 1);  // prefetch next tile (other buffer)
    char* Kc = smem + 16384 + cur * 8192;
    char* Vc = smem + 32768 + cur * 8192;

    // S = Q K^T  (k-tile of 64 rows)
    f32x4 s[2][4] = {};
    __builtin_amdgcn_s_setprio(1);
#pragma unroll
    for (int kk = 0; kk < 2; ++kk) {
#pragma unroll
      for (int nf = 0; nf < 4; ++nf) {
        int rk = nf * 16 + lr;
        bf16x8 bk = *(const bf16x8*)(Kc + rk * 128 + (((kk * 4 + lg) ^ (rk & 7)) << 4));
        s[0][nf] = __builtin_amdgcn_mfma_f32_16x16x32_bf16(aq[kk][0], bk, s[0][nf], 0, 0, 0);
        s[1][nf] = __builtin_amdgcn_mfma_f32_16x16x32_bf16(aq[kk][1], bk, s[1][nf], 0, 0, 0);
      }
    }
    __builtin_amdgcn_s_setprio(0);

    // online softmax; rows: w*32+mf*16+lg*4+r, 16 lanes (lr) share a row
#pragma unroll
    for (int mf = 0; mf < 2; ++mf) {
#pragma unroll
      for (int r = 0; r < 4; ++r) {
        float mx = fmaxf(fmaxf(s[mf][0][r], s[mf][1][r]), fmaxf(s[mf][2][r], s[mf][3][r]));
        mx *= 0.125f;
        mx = fmaxf(mx, __shfl_xor(mx, 1));
        mx = fmaxf(mx, __shfl_xor(mx, 2));
        mx = fmaxf(mx, __shfl_xor(mx, 4));
        mx = fmaxf(mx, __shfl_xor(mx, 8));
        float mnew = fmaxf(m_run[mf][r], mx);
        float cr = __expf(m_run[mf][r] - mnew);
        float lsum = 0.0f;
#pragma unroll
        for (int nf = 0; nf < 4; ++nf) {
          float p = __expf(s[mf][nf][r] * 0.125f - mnew);
          s[mf][nf][r] = p;
          lsum += p;
        }
        lsum += __shfl_xor(lsum, 1);
        lsum += __shfl_xor(lsum, 2);
        lsum += __shfl_xor(lsum, 4);
        lsum += __shfl_xor(lsum, 8);
        l_run[mf][r] = l_run[mf][r] * cr + lsum;
        m_run[mf][r] = mnew;
#pragma unroll
        for (int df = 0; df < 4; ++df) acc[mf][df][r] *= cr;
      }
      // P -> LDS (wave-local stripe; no barrier needed)
#pragma unroll
      for (int nf = 0; nf < 4; ++nf)
#pragma unroll
        for (int r = 0; r < 4; ++r) {
          int row = w * 32 + mf * 16 + lg * 4 + r;
          int col2 = (nf * 16 + lr) * 2;
          int slot = col2 >> 4;
          *(__bf16*)(Ps + row * 128 + (((slot ^ (row & 7)) << 4) | (col2 & 15))) =
              (__bf16)s[mf][nf][r];
        }
    }

    // O += P V   (B rows are V^T rows: d-major)
    __builtin_amdgcn_s_setprio(1);
#pragma unroll
    for (int kk = 0; kk < 2; ++kk) {
      bf16x8 ap[2];
#pragma unroll
      for (int mf = 0; mf < 2; ++mf) {
        int row = w * 32 + mf * 16 + lr;
        ap[mf] = *(const bf16x8*)(Ps + row * 128 + (((kk * 4 + lg) ^ (row & 7)) << 4));
      }
#pragma unroll
      for (int df = 0; df < 4; ++df) {
        int rv = df * 16 + lr;
        bf16x8 bv = *(const bf16x8*)(Vc + rv * 128 + (((kk * 4 + lg) ^ (rv & 7)) << 4));
        acc[0][df] = __builtin_amdgcn_mfma_f32_16x16x32_bf16(ap[0], bv, acc[0][df], 0, 0, 0);
        acc[1][df] = __builtin_amdgcn_mfma_f32_16x16x32_bf16(ap[1], bv, acc[1][df], 0, 0, 0);
      }
    }
    __builtin_amdgcn_s_setprio(0);

    __syncthreads();       // drain prefetch vmcnt + release buffers
    cur ^= 1;
  }

  const int b = bh >> 4, h = bh & 15;
#pragma unroll
  for (int mf = 0; mf < 2; ++mf) {
#pragma unroll
    for (int df = 0; df < 4; ++df) {
#pragma unroll
      for (int r = 0; r < 4; ++r) {
        int l = fq * 128 + w * 32 + mf * 16 + lg * 4 + r;
        int d = df * 16 + lr;
        float o = acc[mf][df][r] / l_run[mf][r];
        ob[((size_t)(b * 2048 + l)) * 1024 + h * 64 + d] = (__bf16)o;
      }
    }
  }
}

// ---------------- launch ----------------
extern "C" void kernel_launch(void* const* d_in, const int* in_sizes, int n_in,
                              void* d_out, int out_size, void* d_ws, size_t ws_size,
                              hipStream_t stream) {
  (void)in_sizes; (void)n_in; (void)out_size; (void)ws_size;
  const float* x    = (const float*)d_in[0];
  const float* Wqkv = (const float*)d_in[1];
  const float* bqkv = (const float*)d_in[2];
  const float* Wout = (const float*)d_in[3];
  const float* bout = (const float*)d_in[4];
  const float* qg   = (const float*)d_in[5];
  const float* kg   = (const float*)d_in[6];

  char* ws = (char*)d_ws;
  __bf16* xb   = (__bf16*)(ws);                 // 4096x1024       (8 MB)
  __bf16* wqb  = (__bf16*)(ws + 8388608);       // 3072x1024       (6 MB)
  __bf16* wob  = (__bf16*)(ws + 14680064);      // 1024x1024       (2 MB)
  __bf16* qbuf = (__bf16*)(ws + 16777216);      // [2][16][2048][64]
  __bf16* kbuf = (__bf16*)(ws + 25165824);
  __bf16* vbuf = (__bf16*)(ws + 33554432);      // V^T: [2][16][64][2048]
  __bf16* aob  = (__bf16*)(ws + 41943040);      // [2][2048][1024]
  float2* rtab = (float2*)(ws + 50331648);      // [2048][32] cos/sin

  cvt_kernel<<<4096, 256, 0, stream>>>(x, xb, 1048576);
  cvt_kernel<<<3072, 256, 0, stream>>>(Wqkv, wqb, 786432);
  cvt_kernel<<<1024, 256, 0, stream>>>(Wout, wob, 262144);
  rope_tab_kernel<<<256, 256, 0, stream>>>(rtab);
  gemm_bt<0><<<768, 256, 0, stream>>>(xb, wqb, 1024, 24, bqkv, qbuf, kbuf, vbuf, nullptr);
  norm_rope_kernel<<<512, 256, 0, stream>>>(qbuf, kbuf, qg, kg, rtab);
  attn_kernel<<<512, 256, 0, stream>>>(qbuf, kbuf, vbuf, aob);
  gemm_bt<1><<<256, 256, 0, stream>>>(aob, wob, 1024, 8, bout, nullptr, nullptr, nullptr, (float*)d_out);
}

// Round 4
// 245.553 us; speedup vs baseline: 1.3786x; 1.1487x over previous
//
#include <hip/hip_runtime.h>
#include <hip/hip_bf16.h>

typedef __bf16 bf16x8 __attribute__((ext_vector_type(8)));
typedef __bf16 bf16x4 __attribute__((ext_vector_type(4)));
typedef float  f32x4  __attribute__((ext_vector_type(4)));

#define GLOBAL_AS __attribute__((address_space(1)))
#define LDS_AS    __attribute__((address_space(3)))

__device__ __forceinline__ void glds16(const void* g, void* l) {
  __builtin_amdgcn_global_load_lds((const GLOBAL_AS void*)g, (LDS_AS void*)l, 16, 0, 0);
}

// ---------------- f32 -> bf16 convert (x, W_qkv, W_out fused) ----------------
__global__ __launch_bounds__(256) void cvt3_kernel(
    const float* __restrict__ a, __bf16* __restrict__ da, int na4,
    const float* __restrict__ b, __bf16* __restrict__ db, int nb4,
    const float* __restrict__ c, __bf16* __restrict__ dc, int nc4) {
  int i = blockIdx.x * 256 + threadIdx.x;
  const float* s; __bf16* d; int j = i;
  if (i < na4) { s = a; d = da; }
  else if ((j = i - na4) < nb4) { s = b; d = db; }
  else if ((j = i - na4 - nb4) < nc4) { s = c; d = dc; }
  else return;
  float4 f = ((const float4*)s)[j];
  bf16x4 o;
  o[0] = (__bf16)f.x; o[1] = (__bf16)f.y; o[2] = (__bf16)f.z; o[3] = (__bf16)f.w;
  ((bf16x4*)d)[j] = o;
}

// ---------------- RoPE cos/sin table: [l][j] l<2048, j<32 ----------------
__global__ __launch_bounds__(256) void rope_tab_kernel(float2* __restrict__ tab) {
  int i = blockIdx.x * 256 + threadIdx.x;   // 0..65535
  int l = i >> 5, j = i & 31;
  float inv = 1.0f / powf(10000.0f, (float)j * (1.0f / 32.0f));
  float ang = (float)l * inv;
  tab[i] = make_float2(cosf(ang), sinf(ang));
}

// ---------------- GEMM C = A * B^T (+bias), A[M,K] bf16, B[N,K] bf16 ----------------
// 128x128 tile, BK=32, 4 waves (2x2), 16x16x32 bf16 MFMA. 1-D grid + XCD swizzle.
// EPI 0: scatter-> q/k [b,h,l,d] bf16, v TRANSPOSED [b,h,d,l] bf16; EPI 1: d_out f32.
template <int EPI>
__global__ __launch_bounds__(256) void gemm_bt(
    const __bf16* __restrict__ A, const __bf16* __restrict__ Bm, int K, int nbn,
    const float* __restrict__ bias,
    __bf16* __restrict__ qo, __bf16* __restrict__ ko, __bf16* __restrict__ vo,
    float* __restrict__ out) {
  __shared__ __bf16 As[128 * 32];
  __shared__ __bf16 Bs[128 * 32];
  const int t = threadIdx.x;
  const int nwg = gridDim.x;
  const int id = blockIdx.x;
  const int swz = (id & 7) * (nwg >> 3) + (id >> 3);
  const int bn = swz % nbn, bm = swz / nbn;
  const int lane = t & 63, w = t >> 6;
  const int wr = w >> 1, wc = w & 1;
  const int lr = lane & 15, lg = lane >> 4;
  const size_t rowA0 = (size_t)bm * 128, rowB0 = (size_t)bn * 128;

  f32x4 acc[4][4] = {};

  for (int k0 = 0; k0 < K; k0 += 32) {
    __syncthreads();
#pragma unroll
    for (int i = 0; i < 2; ++i) {
      int c = t + i * 256;
      int rr = c >> 2, c8 = (c & 3) * 8;
      glds16(A + (rowA0 + rr) * K + k0 + c8, As + c * 8);
      glds16(Bm + (rowB0 + rr) * K + k0 + c8, Bs + c * 8);
    }
    __syncthreads();
    bf16x8 af[4], bfr[4];
#pragma unroll
    for (int i = 0; i < 4; ++i) {
      af[i]  = *(const bf16x8*)&As[(wr * 64 + i * 16 + lr) * 32 + lg * 8];
      bfr[i] = *(const bf16x8*)&Bs[(wc * 64 + i * 16 + lr) * 32 + lg * 8];
    }
#pragma unroll
    for (int mi = 0; mi < 4; ++mi)
#pragma unroll
      for (int ni = 0; ni < 4; ++ni)
        acc[mi][ni] = __builtin_amdgcn_mfma_f32_16x16x32_bf16(af[mi], bfr[ni], acc[mi][ni], 0, 0, 0);
  }

#pragma unroll
  for (int mi = 0; mi < 4; ++mi) {
    int m0 = bm * 128 + wr * 64 + mi * 16 + lg * 4;
#pragma unroll
    for (int ni = 0; ni < 4; ++ni) {
      int n = bn * 128 + wc * 64 + ni * 16 + lr;
      float bb = bias[n];
      if constexpr (EPI == 0) {
        int sect = n >> 10, h = (n >> 6) & 15, d = n & 63;
#pragma unroll
        for (int r = 0; r < 4; ++r) {
          int m = m0 + r;
          int b_ = m >> 11, l = m & 2047;
          float val = acc[mi][ni][r] + bb;
          if (sect == 2)
            vo[((size_t)((b_ * 16 + h) * 64 + d)) * 2048 + l] = (__bf16)val;   // V^T [b,h,d,l]
          else {
            __bf16* dst = sect ? ko : qo;
            dst[(((size_t)(b_ * 16 + h)) * 2048 + l) * 64 + d] = (__bf16)val;
          }
        }
      } else {
#pragma unroll
        for (int r = 0; r < 4; ++r) {
          int m = m0 + r;
          out[(size_t)m * 1024 + n] = acc[mi][ni][r] + bb;
        }
      }
    }
  }
}

// ---------------- RMSNorm + RoPE, in-place on q and k ([b][h][l][64] bf16) ----------------
__global__ __launch_bounds__(256) void norm_rope_kernel(
    __bf16* __restrict__ qb, __bf16* __restrict__ kb,
    const float* __restrict__ qg, const float* __restrict__ kg,
    const float2* __restrict__ tab) {
  const int lane = threadIdx.x & 63;
  const int w0 = (blockIdx.x * 256 + threadIdx.x) >> 6;
  const int nw = gridDim.x * 4;
  for (int rid = w0; rid < 131072; rid += nw) {
    const int tsel = rid >> 16;      // 0: q, 1: k
    const int r = rid & 65535;
    __bf16* buf = tsel ? kb : qb;
    const float* g = tsel ? kg : qg;
    const int l = r & 2047;
    const size_t base = (size_t)r * 64;
    float v = (float)buf[base + lane];
    float ss = v * v;
    ss += __shfl_xor(ss, 1);  ss += __shfl_xor(ss, 2);  ss += __shfl_xor(ss, 4);
    ss += __shfl_xor(ss, 8);  ss += __shfl_xor(ss, 16); ss += __shfl_xor(ss, 32);
    float tnorm = v * rsqrtf(ss * (1.0f / 64.0f) + 1e-6f) * g[lane];
    float2 cs = tab[l * 32 + (lane & 31)];
    float partner = __shfl_xor(tnorm, 32);
    float o = (lane < 32) ? (tnorm * cs.x - partner * cs.y)
                          : (tnorm * cs.x + partner * cs.y);
    buf[base + lane] = (__bf16)o;
  }
}

// ---------------- flash attention, swapped-QK^T, in-register softmax ----------------
// 1-D grid 512 blocks (load-balanced pairing), 4 waves x 32 q-rows. KVBLK=64.
// LDS 32K: [0,16K) Q-stage then P tile; [16K,24K) K tile; [24K,32K) V^T tile.
// K/V single-buffered; next tile async-staged global->reg early, ds_write after barrier (T14).
__global__ __launch_bounds__(256) void attn_kernel(
    const __bf16* __restrict__ qb, const __bf16* __restrict__ kb,
    const __bf16* __restrict__ vT, __bf16* __restrict__ ob) {
  __shared__ char smem[32768];
  char* Qs = smem;                       // [128][64] bf16; becomes P [128][64] after hoist
  char* Ps = smem;
  char* Ks = smem + 16384;               // [64][64] bf16
  char* Vs = smem + 24576;               // [64][64] bf16 (V^T: rows=d, cols=k)

  const int id = blockIdx.x;             // 0..511
  const int rank = (id < 256) ? id : 767 - id;   // complementary-cost pairing per CU
  const int fq = rank >> 5;
  const int bh = rank & 31;
  const int t = threadIdx.x;
  const int lane = t & 63;
  const int w = t >> 6;
  const int lr = lane & 15, lg = lane >> 4;
  const size_t hoff = (size_t)bh * (2048 * 64);

  const int fkStart = (fq == 15) ? 2 : 0;
  const int fkEnd = (fq + 1) * 2;        // exclusive, 64-row k-tiles

  // stage Q + first K/V tile (pre-swizzled source, linear LDS dest)
#pragma unroll
  for (int i = 0; i < 4; ++i) {
    int c = t + i * 256;
    int row = c >> 3, sl = c & 7;
    int sp = sl ^ (row & 7);
    glds16(qb + hoff + (size_t)(fq * 128 + row) * 64 + sp * 8, Qs + c * 16);
  }
#pragma unroll
  for (int i = 0; i < 2; ++i) {
    int c = t + i * 256;
    int row = c >> 3, sl = c & 7;
    int sp = sl ^ (row & 7);
    glds16(kb + hoff + (size_t)(fkStart * 64 + row) * 64 + sp * 8, Ks + c * 16);
    glds16(vT + hoff + (size_t)row * 2048 + fkStart * 64 + sp * 8, Vs + c * 16);
  }
  __syncthreads();

  // hoist Q fragments (B-operand: lane holds Q[q=lr(+16mf)][dh=lg*8+reg])
  bf16x8 aq[2][2];
#pragma unroll
  for (int kk = 0; kk < 2; ++kk)
#pragma unroll
    for (int mf = 0; mf < 2; ++mf) {
      int row = w * 32 + mf * 16 + lr;
      aq[kk][mf] = *(const bf16x8*)(Qs + row * 128 + (((kk * 4 + lg) ^ (row & 7)) << 4));
    }
  __syncthreads();                       // Q region becomes P region

  f32x4 acc[2][4] = {};                  // O^T: [mf(q)][df(d)], row=d in frag, col=q
  float m_run[2] = {-INFINITY, -INFINITY};
  float l_run[2] = {0.0f, 0.0f};

  for (int fk = fkStart; fk < fkEnd; ++fk) {
    // T14: issue next tile's K/V global->reg loads early
    bf16x8 kr[2], vr[2];
    const bool havePref = (fk + 1 < fkEnd);
    if (havePref) {
#pragma unroll
      for (int i = 0; i < 2; ++i) {
        int c = t + i * 256;
        int row = c >> 3, sl = c & 7;
        int sp = sl ^ (row & 7);
        kr[i] = *(const bf16x8*)(kb + hoff + (size_t)((fk + 1) * 64 + row) * 64 + sp * 8);
        vr[i] = *(const bf16x8*)(vT + hoff + (size_t)row * 2048 + (fk + 1) * 64 + sp * 8);
      }
    }

    // S^T = K Q^T : st[mf][nf], row=k (nf*16+lg*4+r), col=q (mf*16+lr)
    f32x4 st[2][4] = {};
    __builtin_amdgcn_s_setprio(1);
#pragma unroll
    for (int kk = 0; kk < 2; ++kk) {
#pragma unroll
      for (int nf = 0; nf < 4; ++nf) {
        int rk = nf * 16 + lr;
        bf16x8 bk = *(const bf16x8*)(Ks + rk * 128 + (((kk * 4 + lg) ^ (rk & 7)) << 4));
        st[0][nf] = __builtin_amdgcn_mfma_f32_16x16x32_bf16(bk, aq[kk][0], st[0][nf], 0, 0, 0);
        st[1][nf] = __builtin_amdgcn_mfma_f32_16x16x32_bf16(bk, aq[kk][1], st[1][nf], 0, 0, 0);
      }
    }
    __builtin_amdgcn_s_setprio(0);

    // in-register online softmax: lane owns q=lr for each mf; k spread over (nf,r) in-lane
    // and lg cross-lane (shfl_xor 16,32).
#pragma unroll
    for (int mf = 0; mf < 2; ++mf) {
      float mx = st[mf][0][0];
#pragma unroll
      for (int nf = 0; nf < 4; ++nf)
#pragma unroll
        for (int r = 0; r < 4; ++r) mx = fmaxf(mx, st[mf][nf][r]);
      mx *= 0.125f;
      mx = fmaxf(mx, __shfl_xor(mx, 16));
      mx = fmaxf(mx, __shfl_xor(mx, 32));
      float mnew = fmaxf(m_run[mf], mx);
      float cr = __expf(m_run[mf] - mnew);
      float lsum = 0.0f;
#pragma unroll
      for (int nf = 0; nf < 4; ++nf)
#pragma unroll
        for (int r = 0; r < 4; ++r) {
          float p = __expf(st[mf][nf][r] * 0.125f - mnew);
          st[mf][nf][r] = p;
          lsum += p;
        }
      lsum += __shfl_xor(lsum, 16);
      lsum += __shfl_xor(lsum, 32);
      l_run[mf] = l_run[mf] * cr + lsum;
      m_run[mf] = mnew;
#pragma unroll
      for (int df = 0; df < 4; ++df) acc[mf][df] *= cr;

      // P^T -> LDS as P[q][k]: lane writes 4 consecutive k (bf16x4, 8B) per nf
#pragma unroll
      for (int nf = 0; nf < 4; ++nf) {
        int row = w * 32 + mf * 16 + lr;
        bf16x4 pw;
#pragma unroll
        for (int r = 0; r < 4; ++r) pw[r] = (__bf16)st[mf][nf][r];
        int slot = nf * 2 + (lg >> 1);
        *(bf16x4*)(Ps + row * 128 + (((slot ^ (row & 7)) << 4) | ((lg & 1) * 8))) = pw;
      }
    }

    // O^T += V^T P^T : A = V^T frag (row=d, k=lg*8+reg), B = P^T frag (k, col=q)
    __builtin_amdgcn_s_setprio(1);
#pragma unroll
    for (int kk = 0; kk < 2; ++kk) {
      bf16x8 ap[2];
#pragma unroll
      for (int mf = 0; mf < 2; ++mf) {
        int row = w * 32 + mf * 16 + lr;
        ap[mf] = *(const bf16x8*)(Ps + row * 128 + (((kk * 4 + lg) ^ (row & 7)) << 4));
      }
#pragma unroll
      for (int df = 0; df < 4; ++df) {
        int rv = df * 16 + lr;
        bf16x8 av = *(const bf16x8*)(Vs + rv * 128 + (((kk * 4 + lg) ^ (rv & 7)) << 4));
        acc[0][df] = __builtin_amdgcn_mfma_f32_16x16x32_bf16(av, ap[0], acc[0][df], 0, 0, 0);
        acc[1][df] = __builtin_amdgcn_mfma_f32_16x16x32_bf16(av, ap[1], acc[1][df], 0, 0, 0);
      }
    }
    __builtin_amdgcn_s_setprio(0);

    __syncthreads();                     // all waves done reading K/V
    if (havePref) {
#pragma unroll
      for (int i = 0; i < 2; ++i) {
        int c = t + i * 256;
        *(bf16x8*)(Ks + c * 16) = kr[i];
        *(bf16x8*)(Vs + c * 16) = vr[i];
      }
      __syncthreads();                   // writes visible before next reads
    }
  }

  // epilogue: O^T -> O; lane has q=lr(+16mf), d=df*16+lg*4+r (consecutive r)
  const int b = bh >> 4, h = bh & 15;
#pragma unroll
  for (int mf = 0; mf < 2; ++mf) {
    float rl = 1.0f / l_run[mf];
    int l = fq * 128 + w * 32 + mf * 16 + lr;
#pragma unroll
    for (int df = 0; df < 4; ++df) {
      bf16x4 ov;
#pragma unroll
      for (int r = 0; r < 4; ++r) ov[r] = (__bf16)(acc[mf][df][r] * rl);
      int d0 = df * 16 + lg * 4;
      *(bf16x4*)(ob + ((size_t)(b * 2048 + l)) * 1024 + h * 64 + d0) = ov;
    }
  }
}

// ---------------- launch ----------------
extern "C" void kernel_launch(void* const* d_in, const int* in_sizes, int n_in,
                              void* d_out, int out_size, void* d_ws, size_t ws_size,
                              hipStream_t stream) {
  (void)in_sizes; (void)n_in; (void)out_size; (void)ws_size;
  const float* x    = (const float*)d_in[0];
  const float* Wqkv = (const float*)d_in[1];
  const float* bqkv = (const float*)d_in[2];
  const float* Wout = (const float*)d_in[3];
  const float* bout = (const float*)d_in[4];
  const float* qg   = (const float*)d_in[5];
  const float* kg   = (const float*)d_in[6];

  char* ws = (char*)d_ws;
  __bf16* xb   = (__bf16*)(ws);                 // 4096x1024       (8 MB)
  __bf16* wqb  = (__bf16*)(ws + 8388608);       // 3072x1024       (6 MB)
  __bf16* wob  = (__bf16*)(ws + 14680064);      // 1024x1024       (2 MB)
  __bf16* qbuf = (__bf16*)(ws + 16777216);      // [2][16][2048][64]
  __bf16* kbuf = (__bf16*)(ws + 25165824);
  __bf16* vbuf = (__bf16*)(ws + 33554432);      // V^T: [2][16][64][2048]
  __bf16* aob  = (__bf16*)(ws + 41943040);      // [2][2048][1024]
  float2* rtab = (float2*)(ws + 50331648);      // [2048][32] cos/sin

  cvt3_kernel<<<8192, 256, 0, stream>>>(x, xb, 1048576, Wqkv, wqb, 786432, Wout, wob, 262144);
  rope_tab_kernel<<<256, 256, 0, stream>>>(rtab);
  gemm_bt<0><<<768, 256, 0, stream>>>(xb, wqb, 1024, 24, bqkv, qbuf, kbuf, vbuf, nullptr);
  norm_rope_kernel<<<512, 256, 0, stream>>>(qbuf, kbuf, qg, kg, rtab);
  attn_kernel<<<512, 256, 0, stream>>>(qbuf, kbuf, vbuf, aob);
  gemm_bt<1><<<256, 256, 0, stream>>>(aob, wob, 1024, 8, bout, nullptr, nullptr, nullptr, (float*)d_out);
}

// Round 5
// 203.650 us; speedup vs baseline: 1.6623x; 1.2058x over previous
//
#include <hip/hip_runtime.h>
#include <hip/hip_bf16.h>

typedef __bf16 bf16x8 __attribute__((ext_vector_type(8)));
typedef __bf16 bf16x4 __attribute__((ext_vector_type(4)));
typedef float  f32x4  __attribute__((ext_vector_type(4)));

#define GLOBAL_AS __attribute__((address_space(1)))
#define LDS_AS    __attribute__((address_space(3)))

__device__ __forceinline__ void glds16(const void* g, void* l) {
  __builtin_amdgcn_global_load_lds((const GLOBAL_AS void*)g, (LDS_AS void*)l, 16, 0, 0);
}

// ---------------- prep: f32->bf16 converts (x, W_qkv, W_out) + RoPE cos/sin table ----------------
__global__ __launch_bounds__(256) void prep_kernel(
    const float* __restrict__ a, __bf16* __restrict__ da, int na4,
    const float* __restrict__ b, __bf16* __restrict__ db, int nb4,
    const float* __restrict__ c, __bf16* __restrict__ dc, int nc4,
    float2* __restrict__ tab) {
  int i = blockIdx.x * 256 + threadIdx.x;
  const float* s; __bf16* d; int j = i;
  if (i < na4) { s = a; d = da; }
  else if ((j = i - na4) < nb4) { s = b; d = db; }
  else if ((j = i - na4 - nb4) < nc4) { s = c; d = dc; }
  else {
    j = i - na4 - nb4 - nc4;
    if (j < 65536) {                     // [l(2048)][j(32)] cos/sin
      int l = j >> 5, jj = j & 31;
      float inv = 1.0f / powf(10000.0f, (float)jj * (1.0f / 32.0f));
      float ang = (float)l * inv;
      tab[j] = make_float2(cosf(ang), sinf(ang));
    }
    return;
  }
  float4 f = ((const float4*)s)[j];
  bf16x4 o;
  o[0] = (__bf16)f.x; o[1] = (__bf16)f.y; o[2] = (__bf16)f.z; o[3] = (__bf16)f.w;
  ((bf16x4*)d)[j] = o;
}

// ---------------- GEMM C = A * B^T (+bias), A[M,K] bf16, B[N,K] bf16 ----------------
// 128x128 tile, BK=32, 4 waves (2x2), 16x16x32 bf16 MFMA. 1-D grid + XCD swizzle.
// EPI 0: fused RMSNorm+RoPE -> q/k [b,h,l,d] bf16; v TRANSPOSED [b,h,d,l] bf16.
// EPI 1: d_out f32.
template <int EPI>
__global__ __launch_bounds__(256) void gemm_bt(
    const __bf16* __restrict__ A, const __bf16* __restrict__ Bm, int K, int nbn,
    const float* __restrict__ bias,
    __bf16* __restrict__ qo, __bf16* __restrict__ ko, __bf16* __restrict__ vo,
    float* __restrict__ out,
    const float* __restrict__ qg, const float* __restrict__ kg,
    const float2* __restrict__ tab) {
  __shared__ __bf16 As[128 * 32];
  __shared__ __bf16 Bs[128 * 32];
  const int t = threadIdx.x;
  const int nwg = gridDim.x;
  const int id = blockIdx.x;
  const int swz = (id & 7) * (nwg >> 3) + (id >> 3);
  const int bn = swz % nbn, bm = swz / nbn;
  const int lane = t & 63, w = t >> 6;
  const int wr = w >> 1, wc = w & 1;
  const int lr = lane & 15, lg = lane >> 4;
  const size_t rowA0 = (size_t)bm * 128, rowB0 = (size_t)bn * 128;

  f32x4 acc[4][4] = {};

  for (int k0 = 0; k0 < K; k0 += 32) {
    __syncthreads();
#pragma unroll
    for (int i = 0; i < 2; ++i) {
      int c = t + i * 256;
      int rr = c >> 2, c8 = (c & 3) * 8;
      glds16(A + (rowA0 + rr) * K + k0 + c8, As + c * 8);
      glds16(Bm + (rowB0 + rr) * K + k0 + c8, Bs + c * 8);
    }
    __syncthreads();
    bf16x8 af[4], bfr[4];
#pragma unroll
    for (int i = 0; i < 4; ++i) {
      af[i]  = *(const bf16x8*)&As[(wr * 64 + i * 16 + lr) * 32 + lg * 8];
      bfr[i] = *(const bf16x8*)&Bs[(wc * 64 + i * 16 + lr) * 32 + lg * 8];
    }
#pragma unroll
    for (int mi = 0; mi < 4; ++mi)
#pragma unroll
      for (int ni = 0; ni < 4; ++ni)
        acc[mi][ni] = __builtin_amdgcn_mfma_f32_16x16x32_bf16(af[mi], bfr[ni], acc[mi][ni], 0, 0, 0);
  }

  // epilogue: C/D layout col=lane&15, row=(lane>>4)*4+reg (m89-verified)
  if constexpr (EPI == 0) {
    // block-uniform: tile n-range [bn*128,(bn+1)*128) -> sect = bn>>3; wave-half head h.
    const int sect = bn >> 3;                // 0:q 1:k 2:v
    const int h = (bn * 2 + wc) & 15;
    float bbv[4];
#pragma unroll
    for (int ni = 0; ni < 4; ++ni) bbv[ni] = bias[bn * 128 + wc * 64 + ni * 16 + lr];
    if (sect < 2) {
      __bf16* dst = sect ? ko : qo;
      const float* g = sect ? kg : qg;
      float gam[4];
#pragma unroll
      for (int ni = 0; ni < 4; ++ni) gam[ni] = g[ni * 16 + lr];   // d = ni*16+lr
#pragma unroll
      for (int mi = 0; mi < 4; ++mi) {
#pragma unroll
        for (int r = 0; r < 4; ++r) {
          int m = bm * 128 + wr * 64 + mi * 16 + lg * 4 + r;
          int b_ = m >> 11, l = m & 2047;
          float v0 = acc[mi][0][r] + bbv[0];
          float v1 = acc[mi][1][r] + bbv[1];
          float v2 = acc[mi][2][r] + bbv[2];
          float v3 = acc[mi][3][r] + bbv[3];
          float ss = v0 * v0 + v1 * v1 + v2 * v2 + v3 * v3;
          ss += __shfl_xor(ss, 1);
          ss += __shfl_xor(ss, 2);
          ss += __shfl_xor(ss, 4);
          ss += __shfl_xor(ss, 8);
          float rinv = rsqrtf(ss * (1.0f / 64.0f) + 1e-6f);
          v0 *= rinv * gam[0]; v1 *= rinv * gam[1];
          v2 *= rinv * gam[2]; v3 *= rinv * gam[3];
          // RoPE: pair (d, d+32) = (ni, ni+2); angle j = d&31
          float2 cs0 = tab[l * 32 + lr];        // ni 0 & 2
          float2 cs1 = tab[l * 32 + 16 + lr];   // ni 1 & 3
          float o0 = v0 * cs0.x - v2 * cs0.y;
          float o2 = v2 * cs0.x + v0 * cs0.y;
          float o1 = v1 * cs1.x - v3 * cs1.y;
          float o3 = v3 * cs1.x + v1 * cs1.y;
          size_t base = ((size_t)(b_ * 16 + h) * 2048 + l) * 64;
          dst[base + lr]      = (__bf16)o0;
          dst[base + 16 + lr] = (__bf16)o1;
          dst[base + 32 + lr] = (__bf16)o2;
          dst[base + 48 + lr] = (__bf16)o3;
        }
      }
    } else {
      // V^T [b,h,d,l]: per thread 4 consecutive l (r) -> 8B stores
#pragma unroll
      for (int mi = 0; mi < 4; ++mi) {
#pragma unroll
        for (int ni = 0; ni < 4; ++ni) {
          int d = ni * 16 + lr;
#pragma unroll
          for (int r = 0; r < 4; ++r) {
            int m = bm * 128 + wr * 64 + mi * 16 + lg * 4 + r;
            int b_ = m >> 11, l = m & 2047;
            vo[((size_t)((b_ * 16 + h) * 64 + d)) * 2048 + l] = (__bf16)(acc[mi][ni][r] + bbv[ni]);
          }
        }
      }
    }
  } else {
#pragma unroll
    for (int mi = 0; mi < 4; ++mi) {
      int m0 = bm * 128 + wr * 64 + mi * 16 + lg * 4;
#pragma unroll
      for (int ni = 0; ni < 4; ++ni) {
        int n = bn * 128 + wc * 64 + ni * 16 + lr;
        float bb = bias[n];
#pragma unroll
        for (int r = 0; r < 4; ++r)
          out[(size_t)(m0 + r) * 1024 + n] = acc[mi][ni][r] + bb;
      }
    }
  }
}

// ---------------- flash attention, swapped-QK^T, in-register softmax ----------------
// 1-D grid 512 blocks (load-balanced pairing), 4 waves x 32 q-rows. KVBLK=64.
// LDS 48K: [0,16K) Q-stage then P; [16K,32K) K dbuf; [32K,48K) V^T dbuf.
// One barrier per tile: ds_write prev-prefetch at iter top, global-load fk+2, compute, barrier.
__global__ __launch_bounds__(256) void attn_kernel(
    const __bf16* __restrict__ qb, const __bf16* __restrict__ kb,
    const __bf16* __restrict__ vT, __bf16* __restrict__ ob) {
  __shared__ char smem[49152];
  char* Qs = smem;                       // [128][64] bf16; becomes P after hoist
  char* Ps = smem;

  const int id = blockIdx.x;             // 0..511
  const int rank = (id < 256) ? id : 767 - id;   // complementary-cost pairing per CU
  const int fq = rank >> 5;
  const int bh = rank & 31;
  const int t = threadIdx.x;
  const int lane = t & 63;
  const int w = t >> 6;
  const int lr = lane & 15, lg = lane >> 4;
  const size_t hoff = (size_t)bh * (2048 * 64);

  const int fkStart = (fq == 15) ? 2 : 0;
  const int fkEnd = (fq + 1) * 2;        // exclusive, 64-row k-tiles

  // stage Q + first K/V tile (pre-swizzled source, linear LDS dest)
#pragma unroll
  for (int i = 0; i < 4; ++i) {
    int c = t + i * 256;
    int row = c >> 3, sl = c & 7;
    int sp = sl ^ (row & 7);
    glds16(qb + hoff + (size_t)(fq * 128 + row) * 64 + sp * 8, Qs + c * 16);
  }
  {
    char* Kd = smem + 16384;
    char* Vd = smem + 32768;
#pragma unroll
    for (int i = 0; i < 2; ++i) {
      int c = t + i * 256;
      int row = c >> 3, sl = c & 7;
      int sp = sl ^ (row & 7);
      glds16(kb + hoff + (size_t)(fkStart * 64 + row) * 64 + sp * 8, Kd + c * 16);
      glds16(vT + hoff + (size_t)row * 2048 + fkStart * 64 + sp * 8, Vd + c * 16);
    }
  }
  // reg-prefetch tile fkStart+1
  bf16x8 kr[2], vr[2];
  if (fkStart + 1 < fkEnd) {
#pragma unroll
    for (int i = 0; i < 2; ++i) {
      int c = t + i * 256;
      int row = c >> 3, sl = c & 7;
      int sp = sl ^ (row & 7);
      kr[i] = *(const bf16x8*)(kb + hoff + (size_t)((fkStart + 1) * 64 + row) * 64 + sp * 8);
      vr[i] = *(const bf16x8*)(vT + hoff + (size_t)row * 2048 + (fkStart + 1) * 64 + sp * 8);
    }
  }
  __syncthreads();

  // hoist Q fragments (B-operand: lane holds Q[q=lr(+16mf)][dh=lg*8+reg])
  bf16x8 aq[2][2];
#pragma unroll
  for (int kk = 0; kk < 2; ++kk)
#pragma unroll
    for (int mf = 0; mf < 2; ++mf) {
      int row = w * 32 + mf * 16 + lr;
      aq[kk][mf] = *(const bf16x8*)(Qs + row * 128 + (((kk * 4 + lg) ^ (row & 7)) << 4));
    }
  __syncthreads();                       // Q region becomes P region

  f32x4 acc[2][4] = {};                  // O^T: [mf(q)][df(d)]
  float m_run[2] = {-INFINITY, -INFINITY};
  float l_run[2] = {0.0f, 0.0f};

  int cur = 0;
  for (int fk = fkStart; fk < fkEnd; ++fk) {
    char* Kc = smem + 16384 + cur * 8192;
    char* Vc = smem + 32768 + cur * 8192;
    // write prev-iteration's reg-prefetch (tile fk+1) into the other buffer
    if (fk + 1 < fkEnd) {
      char* Kd = smem + 16384 + (cur ^ 1) * 8192;
      char* Vd = smem + 32768 + (cur ^ 1) * 8192;
#pragma unroll
      for (int i = 0; i < 2; ++i) {
        int c = t + i * 256;
        *(bf16x8*)(Kd + c * 16) = kr[i];
        *(bf16x8*)(Vd + c * 16) = vr[i];
      }
    }
    // issue global loads for tile fk+2
    if (fk + 2 < fkEnd) {
#pragma unroll
      for (int i = 0; i < 2; ++i) {
        int c = t + i * 256;
        int row = c >> 3, sl = c & 7;
        int sp = sl ^ (row & 7);
        kr[i] = *(const bf16x8*)(kb + hoff + (size_t)((fk + 2) * 64 + row) * 64 + sp * 8);
        vr[i] = *(const bf16x8*)(vT + hoff + (size_t)row * 2048 + (fk + 2) * 64 + sp * 8);
      }
    }

    // S^T = K Q^T : st[mf][nf], row=k (nf*16+lg*4+r), col=q (mf*16+lr)
    f32x4 st[2][4] = {};
    __builtin_amdgcn_s_setprio(1);
#pragma unroll
    for (int kk = 0; kk < 2; ++kk) {
#pragma unroll
      for (int nf = 0; nf < 4; ++nf) {
        int rk = nf * 16 + lr;
        bf16x8 bk = *(const bf16x8*)(Kc + rk * 128 + (((kk * 4 + lg) ^ (rk & 7)) << 4));
        st[0][nf] = __builtin_amdgcn_mfma_f32_16x16x32_bf16(bk, aq[kk][0], st[0][nf], 0, 0, 0);
        st[1][nf] = __builtin_amdgcn_mfma_f32_16x16x32_bf16(bk, aq[kk][1], st[1][nf], 0, 0, 0);
      }
    }
    __builtin_amdgcn_s_setprio(0);

    // in-register online softmax; lane owns q=lr per mf; k over (nf,r) in-lane + lg cross-lane
#pragma unroll
    for (int mf = 0; mf < 2; ++mf) {
      float mx = st[mf][0][0];
#pragma unroll
      for (int nf = 0; nf < 4; ++nf)
#pragma unroll
        for (int r = 0; r < 4; ++r) mx = fmaxf(mx, st[mf][nf][r]);
      mx *= 0.125f;
      mx = fmaxf(mx, __shfl_xor(mx, 16));
      mx = fmaxf(mx, __shfl_xor(mx, 32));
      // T13 defer-max: only rescale when some row grew by > 8
      float mnew = m_run[mf], cr = 1.0f;
      if (__any(mx > m_run[mf] + 8.0f)) {
        mnew = fmaxf(m_run[mf], mx);
        cr = __expf(m_run[mf] - mnew);
#pragma unroll
        for (int df = 0; df < 4; ++df) acc[mf][df] *= cr;
      }
      float lsum = 0.0f;
#pragma unroll
      for (int nf = 0; nf < 4; ++nf)
#pragma unroll
        for (int r = 0; r < 4; ++r) {
          float p = __expf(st[mf][nf][r] * 0.125f - mnew);
          st[mf][nf][r] = p;
          lsum += p;
        }
      lsum += __shfl_xor(lsum, 16);
      lsum += __shfl_xor(lsum, 32);
      l_run[mf] = l_run[mf] * cr + lsum;
      m_run[mf] = mnew;

      // P^T -> LDS as P[q][k]: lane writes 4 consecutive k (bf16x4, 8B) per nf
#pragma unroll
      for (int nf = 0; nf < 4; ++nf) {
        int row = w * 32 + mf * 16 + lr;
        bf16x4 pw;
#pragma unroll
        for (int r = 0; r < 4; ++r) pw[r] = (__bf16)st[mf][nf][r];
        int slot = nf * 2 + (lg >> 1);
        *(bf16x4*)(Ps + row * 128 + (((slot ^ (row & 7)) << 4) | ((lg & 1) * 8))) = pw;
      }
    }

    // O^T += V^T P^T : A = V^T frag (row=d), B = P^T frag (col=q)
    __builtin_amdgcn_s_setprio(1);
#pragma unroll
    for (int kk = 0; kk < 2; ++kk) {
      bf16x8 ap[2];
#pragma unroll
      for (int mf = 0; mf < 2; ++mf) {
        int row = w * 32 + mf * 16 + lr;
        ap[mf] = *(const bf16x8*)(Ps + row * 128 + (((kk * 4 + lg) ^ (row & 7)) << 4));
      }
#pragma unroll
      for (int df = 0; df < 4; ++df) {
        int rv = df * 16 + lr;
        bf16x8 av = *(const bf16x8*)(Vc + rv * 128 + (((kk * 4 + lg) ^ (rv & 7)) << 4));
        acc[0][df] = __builtin_amdgcn_mfma_f32_16x16x32_bf16(av, ap[0], acc[0][df], 0, 0, 0);
        acc[1][df] = __builtin_amdgcn_mfma_f32_16x16x32_bf16(av, ap[1], acc[1][df], 0, 0, 0);
      }
    }
    __builtin_amdgcn_s_setprio(0);

    __syncthreads();                     // reads of buf[cur] done + new writes visible
    cur ^= 1;
  }

  // epilogue: O^T -> O; lane has q=lr(+16mf), d=df*16+lg*4+r
  const int b = bh >> 4, h = bh & 15;
#pragma unroll
  for (int mf = 0; mf < 2; ++mf) {
    float rl = 1.0f / l_run[mf];
    int l = fq * 128 + w * 32 + mf * 16 + lr;
#pragma unroll
    for (int df = 0; df < 4; ++df) {
      bf16x4 ov;
#pragma unroll
      for (int r = 0; r < 4; ++r) ov[r] = (__bf16)(acc[mf][df][r] * rl);
      int d0 = df * 16 + lg * 4;
      *(bf16x4*)(ob + ((size_t)(b * 2048 + l)) * 1024 + h * 64 + d0) = ov;
    }
  }
}

// ---------------- launch ----------------
extern "C" void kernel_launch(void* const* d_in, const int* in_sizes, int n_in,
                              void* d_out, int out_size, void* d_ws, size_t ws_size,
                              hipStream_t stream) {
  (void)in_sizes; (void)n_in; (void)out_size; (void)ws_size;
  const float* x    = (const float*)d_in[0];
  const float* Wqkv = (const float*)d_in[1];
  const float* bqkv = (const float*)d_in[2];
  const float* Wout = (const float*)d_in[3];
  const float* bout = (const float*)d_in[4];
  const float* qg   = (const float*)d_in[5];
  const float* kg   = (const float*)d_in[6];

  char* ws = (char*)d_ws;
  __bf16* xb   = (__bf16*)(ws);                 // 4096x1024       (8 MB)
  __bf16* wqb  = (__bf16*)(ws + 8388608);       // 3072x1024       (6 MB)
  __bf16* wob  = (__bf16*)(ws + 14680064);      // 1024x1024       (2 MB)
  __bf16* qbuf = (__bf16*)(ws + 16777216);      // [2][16][2048][64]
  __bf16* kbuf = (__bf16*)(ws + 25165824);
  __bf16* vbuf = (__bf16*)(ws + 33554432);      // V^T: [2][16][64][2048]
  __bf16* aob  = (__bf16*)(ws + 41943040);      // [2][2048][1024]
  float2* rtab = (float2*)(ws + 50331648);      // [2048][32] cos/sin

  // 2097152 cvt quads + 65536 rope entries = 2162688 items -> 8448 blocks
  prep_kernel<<<8448, 256, 0, stream>>>(x, xb, 1048576, Wqkv, wqb, 786432,
                                        Wout, wob, 262144, rtab);
  gemm_bt<0><<<768, 256, 0, stream>>>(xb, wqb, 1024, 24, bqkv, qbuf, kbuf, vbuf, nullptr,
                                      qg, kg, rtab);
  attn_kernel<<<512, 256, 0, stream>>>(qbuf, kbuf, vbuf, aob);
  gemm_bt<1><<<256, 256, 0, stream>>>(aob, wob, 1024, 8, bout, nullptr, nullptr, nullptr,
                                      (float*)d_out, nullptr, nullptr, nullptr);
}